// Round 15
// baseline (27.232 us; speedup 1.0000x reference)
//
#include <hip/hip_runtime.h>

// ParticleI2cCell: pairwise Gaussian loglik (P x P, D=4) + two row-LSEs.
// smoothed[i] = log(sum_j e_ij*exp(w_j)) - log(sum_j e_ij*exp(lw_j))
// e_ij = exp(m_i . s_j - ||s_j||^2/2)   [exp(-||m_i||^2/2) cancels in the
// log-ratio and is dropped].
//
// R13 lesson: every structure lands at ~25-27us; R11 proved marginal VALU
// ops cost full nominal issue time => treat as issue-bound and cut the
// per-pair instruction count. R14/R15: v_dot2_f32_f16 halves the t-compute
// (2 instr for 4 MACs) and cn is folded into the per-j weights
// (elw' = exp2(lw*L2E + cn)), so per pair = 2 dot2 + 1 exp2 + 2 fmaf = 5
// instructions (was 9). f16 only on the dot inputs: |t| error ~0.05 log2,
// far under the 0.18 absmax threshold; all sums stay fp32.
// (R14 compile fix: cvt_pkrtz returns __fp16-based vector, not _Float16.)

constexpr float LOG2E = 1.4426950408889634f;
constexpr float LN2   = 0.6931471805599453f;

typedef __fp16 h2 __attribute__((ext_vector_type(2)));

// ---------------- single fused kernel --------------------------------------
// grid = P/TR = 1024 blocks of 256 -> 4 blocks/CU, 16 waves/CU.
// Thread t sweeps j = t + BLOCK*it (32 iters at P=8192).
template <int TR, int BLOCK>
__global__ __launch_bounds__(BLOCK, 4) void fused_all(
    const float* __restrict__ particles,   // [P][6]
    const float* __restrict__ samples,     // [P][4]
    const float* __restrict__ weights,     // [P]
    const float* __restrict__ log_weights, // [P]
    const float* __restrict__ A,           // [4][4]
    const float* __restrict__ B,           // [4][2]
    const float* __restrict__ log_sigma,   // [4]
    float* __restrict__ out, int P)
{
    constexpr int NW = BLOCK / 64;

    const int tid  = threadIdx.x;
    const int lane = tid & 63;
    const int wv   = tid >> 6;
    const int rowBase = blockIdx.x * TR;

    // ---- per-block uniform setup ----
    // C_k = L2E * inv_sigma_k^2 (scales the j-side); means stay raw on i-side.
    float C[4];
#pragma unroll
    for (int k = 0; k < 4; ++k) {
        float iv = __builtin_amdgcn_exp2f(-log_sigma[k] * LOG2E);
        C[k] = LOG2E * iv * iv;
    }

    // row means -> packed f16 pairs (2 VGPRs per row)
    h2 mh01[TR], mh23[TR];
    float a1[TR], a2[TR];
#pragma unroll
    for (int r = 0; r < TR; ++r) {
        const float* pr = particles + (size_t)(rowBase + r) * 6;
        float x0 = pr[0], x1 = pr[1], x2 = pr[2], x3 = pr[3];
        float u0 = pr[4], u1 = pr[5];
        float mk[4];
#pragma unroll
        for (int k = 0; k < 4; ++k) {
            float mean =       A[k*4+0] * x0;
            mean = fmaf(A[k*4+1], x1, mean);
            mean = fmaf(A[k*4+2], x2, mean);
            mean = fmaf(A[k*4+3], x3, mean);
            mean = fmaf(B[k*2+0], u0, mean);
            mean = fmaf(B[k*2+1], u1, mean);
            mk[k] = mean;
        }
        mh01[r] = __builtin_amdgcn_cvt_pkrtz(mk[0], mk[1]);
        mh23[r] = __builtin_amdgcn_cvt_pkrtz(mk[2], mk[3]);
        a1[r] = 0.f;
        a2[r] = 0.f;
    }

    // ---- hot loop ----
    const float4* sf = reinterpret_cast<const float4*>(samples);
    const int iters = P / BLOCK;     // 32 at P=8192
#pragma unroll 4
    for (int it = 0; it < iters; ++it) {
        const int j = it * BLOCK + tid;
        float4 sv = sf[j];
        float w  = weights[j];
        float lw = log_weights[j];

        // j-side prep (amortized over TR rows):
        // hs_k = C_k * s_k  (so dot(m, hs) = L2E * sum inv2*m*s)
        float hs0 = C[0] * sv.x, hs1 = C[1] * sv.y;
        float hs2 = C[2] * sv.z, hs3 = C[3] * sv.w;
        h2 h01 = __builtin_amdgcn_cvt_pkrtz(hs0, hs1);
        h2 h23 = __builtin_amdgcn_cvt_pkrtz(hs2, hs3);
        // cn = -0.5 * L2E * sum inv2 * s^2  (log2-space)
        float cn = hs0 * sv.x;
        cn = fmaf(hs1, sv.y, cn);
        cn = fmaf(hs2, sv.z, cn);
        cn = fmaf(hs3, sv.w, cn);
        cn = -0.5f * cn;
        // fold cn into the weights: one exp2 each
        float elw = __builtin_amdgcn_exp2f(fmaf(lw, LOG2E, cn));
        float ew  = __builtin_amdgcn_exp2f(fmaf(w,  LOG2E, cn));

#pragma unroll
        for (int r = 0; r < TR; ++r) {
            float t = __builtin_amdgcn_fdot2(mh23[r], h23, 0.f, false);
            t = __builtin_amdgcn_fdot2(mh01[r], h01, t, false);
            float e = __builtin_amdgcn_exp2f(t);
            a1[r] = fmaf(e, elw, a1[r]);
            a2[r] = fmaf(e, ew,  a2[r]);
        }
    }

    // ---- 64-lane butterfly per row (fixed order -> deterministic) ----
#pragma unroll
    for (int r = 0; r < TR; ++r) {
#pragma unroll
        for (int mask = 32; mask >= 1; mask >>= 1) {
            a1[r] += __shfl_xor(a1[r], mask, 64);
            a2[r] += __shfl_xor(a2[r], mask, 64);
        }
    }

    // ---- cross-wave combine via small LDS, fixed order ----
    __shared__ float red[NW][2 * TR];
    if (lane == 0) {
#pragma unroll
        for (int r = 0; r < TR; ++r) {
            red[wv][r]      = a1[r];
            red[wv][TR + r] = a2[r];
        }
    }
    __syncthreads();
    if (tid < TR) {
        float s1 = 0.f, s2 = 0.f;
#pragma unroll
        for (int w = 0; w < NW; ++w) {
            s1 += red[w][tid];
            s2 += red[w][TR + tid];
        }
        out[rowBase + tid] =
            (__builtin_amdgcn_logf(s2) - __builtin_amdgcn_logf(s1)) * LN2;
    }
}

extern "C" void kernel_launch(void* const* d_in, const int* in_sizes, int n_in,
                              void* d_out, int out_size, void* d_ws, size_t ws_size,
                              hipStream_t stream)
{
    const float* particles   = (const float*)d_in[0];
    const float* samples     = (const float*)d_in[1];
    const float* weights     = (const float*)d_in[2];
    const float* log_weights = (const float*)d_in[3];
    const float* A           = (const float*)d_in[4];
    const float* B           = (const float*)d_in[5];
    const float* log_sigma   = (const float*)d_in[6];

    const int P = in_sizes[2];  // weights is (P,)

    constexpr int BLOCK = 256, TR = 8;

    fused_all<TR, BLOCK><<<P / TR, BLOCK, 0, stream>>>(
        particles, samples, weights, log_weights, A, B, log_sigma,
        (float*)d_out, P);
}